// Round 4
// baseline (239.564 us; speedup 1.0000x reference)
//
#include <hip/hip_runtime.h>
#include <math.h>

// Batched expm of 4x4 fp32 matrices: out[m] = expm(A[m] * t[m / S]).
// Scaling-and-squaring identical in structure to the reference:
//   s = clip(ceil(log2(max(||Qt||_inf,1e-30)/0.5)), 0, 16)
//   As = Qt * 2^-s ; P = Taylor(As) ; P = P^(2^s)
// Taylor evaluated to degree 9 via Paterson-Stockmeyer (4 matmuls instead of 9
// sequential ones; truncation 0.5^10/10! ~ 2.7e-10 rel, below fp32 noise).
//
// Round-3 lesson: VGPR stayed 44 -> the compiler SANK the "prefetched" loads
// past the first matrix's compute; the ILP never existed. Rounds 0/2/3 all
// plateau at 80-87us, ~2.4 TB/s effective, VALU<36%, occ<52% -> latency-bound
// (Little's law: ~3 MB in flight vs ~5.7 MB needed for 6 TB/s @ ~900ns).
// This version: grid-stride pipeline, KITER matrices/thread, prefetch pinned
// above compute with sched_barrier(0) (clamped addr, no control flow so it
// can't be merged/sunk), __launch_bounds__(256,6) for 24 resident waves/CU.

typedef float f4 __attribute__((ext_vector_type(4)));

constexpr int TPB   = 256;   // threads per block
constexpr int KITER = 4;     // matrices per thread (strided coalesced sweeps)

__device__ __forceinline__ void mm4(float* __restrict__ D,
                                    const float* __restrict__ X,
                                    const float* __restrict__ Y)
{
    #pragma unroll
    for (int i = 0; i < 4; ++i) {
        const float x0 = X[4*i+0], x1 = X[4*i+1];
        const float x2 = X[4*i+2], x3 = X[4*i+3];
        #pragma unroll
        for (int j = 0; j < 4; ++j) {
            float v = x0 * Y[j];
            v = __builtin_fmaf(x1, Y[4+j],  v);
            v = __builtin_fmaf(x2, Y[8+j],  v);
            v = __builtin_fmaf(x3, Y[12+j], v);
            D[4*i+j] = v;
        }
    }
}

// expm of one 4x4 given its raw rows r[4] and the (uniform) time t.
__device__ __forceinline__ void expm4_one(const f4 r[4], float t, f4 o[4])
{
    // ---- infinity norm of Qt = A*t as (max abs row sum of A) * |t| ----
    const float at = fabsf(t);
    float nrm = 0.0f;
    #pragma unroll
    for (int i = 0; i < 4; ++i) {
        float rs = fabsf(r[i].x) + fabsf(r[i].y) + fabsf(r[i].z) + fabsf(r[i].w);
        nrm = fmaxf(nrm, rs);
    }
    nrm *= at;

    // ---- si = clip(ceil(log2(max(nrm,1e-30)*2)), 0, 16) via exponent bits:
    //      x = 2^e*m, m in [1,2)  =>  ceil(log2 x) = e + (m != 1).
    //      Exact (no transcendentals, shorter serial prologue chain). ----
    const float    x = fmaxf(nrm, 1e-30f) * 2.0f;
    const unsigned u = __float_as_uint(x);
    int si = (int)(u >> 23) - 127 + ((u & 0x7fffffu) != 0u);
    si = si < 0 ? 0 : (si > 16 ? 16 : si);
    const float c = t * __uint_as_float((unsigned)(127 - si) << 23); // t * 2^-si

    float a[16];
    #pragma unroll
    for (int i = 0; i < 4; ++i) {
        a[4*i+0] = r[i].x * c;
        a[4*i+1] = r[i].y * c;
        a[4*i+2] = r[i].z * c;
        a[4*i+3] = r[i].w * c;
    }

    // ---- powers ----
    float A2[16], A3[16];
    mm4(A2, a, a);     // As^2
    mm4(A3, A2, a);    // As^3

    // ---- Paterson-Stockmeyer groups ----
    constexpr float C2 = 1.0f/2.0f,     C3 = 1.0f/6.0f;
    constexpr float C4 = 1.0f/24.0f,    C5 = 1.0f/120.0f;
    constexpr float C6 = 1.0f/720.0f,   C7 = 1.0f/5040.0f;
    constexpr float C8 = 1.0f/40320.0f, C9 = 1.0f/362880.0f;

    float G[16], HI[16], PI[16];
    #pragma unroll
    for (int i = 0; i < 16; ++i) {
        G[i]  = __builtin_fmaf(C9, A3[i],
                __builtin_fmaf(C8, A2[i], C7 * a[i]));
        HI[i] = __builtin_fmaf(C5, A2[i], C4 * a[i]);
        PI[i] = __builtin_fmaf(C2, A2[i], a[i]);
    }
    G[0]  += C6; G[5]  += C6; G[10] += C6; G[15] += C6;
    HI[0] += C3; HI[5] += C3; HI[10] += C3; HI[15] += C3;
    PI[0] += 1.0f; PI[5] += 1.0f; PI[10] += 1.0f; PI[15] += 1.0f;
    // a, A2 now dead.

    // ---- H = G*A3 + HI (in place over HI) ----
    float H[16];
    #pragma unroll
    for (int i = 0; i < 4; ++i) {
        const float g0 = G[4*i+0], g1 = G[4*i+1];
        const float g2 = G[4*i+2], g3 = G[4*i+3];
        #pragma unroll
        for (int j = 0; j < 4; ++j) {
            float v = HI[4*i+j];
            v = __builtin_fmaf(g0, A3[j],    v);
            v = __builtin_fmaf(g1, A3[4+j],  v);
            v = __builtin_fmaf(g2, A3[8+j],  v);
            v = __builtin_fmaf(g3, A3[12+j], v);
            H[4*i+j] = v;
        }
    }

    // ---- P = H*A3 + PI ----
    float P[16];
    #pragma unroll
    for (int i = 0; i < 4; ++i) {
        const float h0 = H[4*i+0], h1 = H[4*i+1];
        const float h2 = H[4*i+2], h3 = H[4*i+3];
        #pragma unroll
        for (int j = 0; j < 4; ++j) {
            float v = PI[4*i+j];
            v = __builtin_fmaf(h0, A3[j],    v);
            v = __builtin_fmaf(h1, A3[4+j],  v);
            v = __builtin_fmaf(h2, A3[8+j],  v);
            v = __builtin_fmaf(h3, A3[12+j], v);
            P[4*i+j] = v;
        }
    }

    // ---- undo scaling: square si times (2x-unrolled ping-pong; wave pays
    //      max si over its lanes) ----
    int it = si;
    while (it >= 2) {
        float Q[16];
        mm4(Q, P, P);
        mm4(P, Q, Q);
        it -= 2;
    }
    if (it) {
        float Q[16];
        mm4(Q, P, P);
        #pragma unroll
        for (int i = 0; i < 16; ++i) P[i] = Q[i];
    }

    #pragma unroll
    for (int i = 0; i < 4; ++i) {
        f4 v; v.x = P[4*i+0]; v.y = P[4*i+1]; v.z = P[4*i+2]; v.w = P[4*i+3];
        o[i] = v;
    }
}

__global__ void __launch_bounds__(TPB, 6) expm4_kernel(
    const float* __restrict__ A,
    const float* __restrict__ tvec,
    float* __restrict__ out,
    int M, int S, int sdivb)   // sdivb = S/TPB if TPB divides S, else 0
{
    const int stride = (int)gridDim.x * TPB;         // matrices per sweep
    const int m0     = (int)blockIdx.x * TPB + (int)threadIdx.x;

    const f4* __restrict__ Ap = reinterpret_cast<const f4*>(A);
    f4*       __restrict__ Op = reinterpret_cast<f4*>(out);

    // ---- prime the pipeline: load matrix for sweep 0 (clamped addr) ----
    const int mi = m0 < M ? m0 : (M - 1);
    f4 rc[4];
    #pragma unroll
    for (int q = 0; q < 4; ++q) rc[q] = Ap[mi * 4 + q];

    int k = 0;
    for (int m = m0; m < M; m += stride, ++k) {
        // ---- t for this sweep (scalar path when blocks sit inside one batch
        //      item; avoids a per-lane integer division) ----
        float t;
        if (sdivb > 0) {
            t = tvec[((unsigned)blockIdx.x + (unsigned)k * gridDim.x) / (unsigned)sdivb];
        } else {
            t = tvec[m / S];
        }

        // ---- prefetch next sweep's matrix: unconditional, clamped address
        //      (always valid memory, no control flow -> nothing to merge) ----
        int mn = m + stride;
        mn = mn < M ? mn : (M - 1);
        f4 rn0 = Ap[mn * 4 + 0];
        f4 rn1 = Ap[mn * 4 + 1];
        f4 rn2 = Ap[mn * 4 + 2];
        f4 rn3 = Ap[mn * 4 + 3];
        // Pin the prefetch above the compute: scheduler may not move any
        // instruction across this point (rounds 0-3: without this, loads sink
        // to their use and latency lands on the critical path).
        __builtin_amdgcn_sched_barrier(0);

        // ---- compute + store current matrix ----
        f4 o[4];
        expm4_one(rc, t, o);
        #pragma unroll
        for (int q = 0; q < 4; ++q) Op[m * 4 + q] = o[q];

        // ---- rotate pipeline ----
        rc[0] = rn0; rc[1] = rn1; rc[2] = rn2; rc[3] = rn3;
    }
}

extern "C" void kernel_launch(void* const* d_in, const int* in_sizes, int n_in,
                              void* d_out, int out_size, void* d_ws, size_t ws_size,
                              hipStream_t stream) {
    const float* A    = (const float*)d_in[0];   // [B, S, 4, 4] fp32
    const float* tvec = (const float*)d_in[1];   // [B] fp32
    float* out        = (float*)d_out;           // [B, S, 4, 4] fp32

    const int B = in_sizes[1];
    const int M = in_sizes[0] / 16;              // total 4x4 matrices
    const int S = M / B;                         // matrices per batch item

    // t is uniform across a block's sweep iff TPB divides S.
    const int sdivb = (S % TPB == 0) ? (S / TPB) : 0;

    int blocks = (M + TPB * KITER - 1) / (TPB * KITER);
    if (blocks < 1) blocks = 1;
    expm4_kernel<<<blocks, TPB, 0, stream>>>(A, tvec, out, M, S, sdivb);
}

// Round 6
// 238.214 us; speedup vs baseline: 1.0057x; 1.0057x over previous
//
#include <hip/hip_runtime.h>
#include <math.h>

// Batched expm of 4x4 fp32 matrices: out[m] = expm(A[m] * t[m / S]).
// Scaling-and-squaring identical in structure to the reference:
//   s = clip(ceil(log2(max(||Qt||_inf,1e-30)/0.5)), 0, 16)
//   As = Qt * 2^-s ; P = Taylor(As) ; P = P^(2^s)
// Taylor: degree-9 Paterson-Stockmeyer (4 matmuls; truncation ~2.7e-10 rel).
//
// Rounds 0-4: every C++-level prefetch was deleted by the compiler (VGPR
// stayed 40/44); all variants plateau at 80-87us / ~2.4 TB/s with VALU<36%,
// occ<52%, while memset hits 6.7 TB/s at 9% occupancy. Diagnosis: per-wave
// memory duty cycle ~30% (8KB burst, then ~1400 dependent-compute cycles with
// nothing in flight) caps BW at ~30% of streaming ceiling.
// This version (round-5 resubmit, hardened): compiler-proof software pipeline.
// ALL global traffic in asm volatile, double-buffered, counted s_waitcnt
// vmcnt(4) (never 0 in the loop) so 8KB/wave stays in flight across every
// compute phase. t is computed from block-uniform SGPRs only (s_load ->
// lgkmcnt; never a compiler VMEM load whose vmcnt(0) would drain the
// pipeline). Packed math: f2 ext-vectors, a*b+c contracts to v_pk_fma_f32.

typedef float f4 __attribute__((ext_vector_type(4)));
typedef float f2 __attribute__((ext_vector_type(2)));

constexpr int TPB   = 256;   // threads per block
constexpr int KITER = 8;     // matrices per thread

// ---- compiler-proof global memory ops -------------------------------------
#define PREF(r, ptr)                                                         \
    asm volatile("global_load_dwordx4 %0, %4, off\n\t"                       \
                 "global_load_dwordx4 %1, %4, off offset:16\n\t"             \
                 "global_load_dwordx4 %2, %4, off offset:32\n\t"             \
                 "global_load_dwordx4 %3, %4, off offset:48"                 \
                 : "=&v"(r##0), "=&v"(r##1), "=&v"(r##2), "=&v"(r##3)        \
                 : "v"((const void*)(ptr)))

// Counted wait: the 4 newest VMEM events (the just-issued prefetch) may stay
// in flight; everything older (this buffer's loads, previous stores) must be
// done. "+v" pass-through makes every consumer depend on this asm, so compute
// cannot be hoisted above the wait.
#define WAITBUF(r)                                                           \
    asm volatile("s_waitcnt vmcnt(4)"                                        \
                 : "+v"(r##0), "+v"(r##1), "+v"(r##2), "+v"(r##3))

#define STORE4(ptr, o0, o1, o2, o3)                                          \
    asm volatile("global_store_dwordx4 %0, %1, off\n\t"                      \
                 "global_store_dwordx4 %0, %2, off offset:16\n\t"            \
                 "global_store_dwordx4 %0, %3, off offset:32\n\t"            \
                 "global_store_dwordx4 %0, %4, off offset:48"                 \
                 :: "v"((void*)(ptr)), "v"(o0), "v"(o1), "v"(o2), "v"(o3)    \
                 : "memory")

// ---- packed-f32 helpers (a*b+c contracts to v_pk_fma_f32) -----------------
__device__ __forceinline__ f2 sp(float s) { f2 v; v.x = s; v.y = s; return v; }

__device__ __forceinline__ void mm4p(f2 D[4][2], const f2 X[4][2],
                                     const f2 Y[4][2])
{
    #pragma unroll
    for (int i = 0; i < 4; ++i) {
        const float x0 = X[i][0].x, x1 = X[i][0].y;
        const float x2 = X[i][1].x, x3 = X[i][1].y;
        #pragma unroll
        for (int p = 0; p < 2; ++p) {
            f2 acc = sp(x0) * Y[0][p];
            acc = sp(x1) * Y[1][p] + acc;
            acc = sp(x2) * Y[2][p] + acc;
            acc = sp(x3) * Y[3][p] + acc;
            D[i][p] = acc;
        }
    }
}

// expm of one 4x4 (rows r0..r3), time t -> rows o0..o3.
__device__ __forceinline__ void expm4_one(f4 r0, f4 r1, f4 r2, f4 r3, float t,
                                          f4& o0, f4& o1, f4& o2, f4& o3)
{
    // ---- infinity norm of Qt = A*t as (max abs row sum of A) * |t| ----
    float nrm = fmaxf(
        fmaxf(fabsf(r0.x)+fabsf(r0.y)+fabsf(r0.z)+fabsf(r0.w),
              fabsf(r1.x)+fabsf(r1.y)+fabsf(r1.z)+fabsf(r1.w)),
        fmaxf(fabsf(r2.x)+fabsf(r2.y)+fabsf(r2.z)+fabsf(r2.w),
              fabsf(r3.x)+fabsf(r3.y)+fabsf(r3.z)+fabsf(r3.w)));
    nrm *= fabsf(t);

    // ---- si = clip(ceil(log2(max(nrm,1e-30)*2)), 0, 16) via exponent bits:
    //      x = 2^e*m, m in [1,2) => ceil(log2 x) = e + (m != 1). Exact. ----
    const float    x = fmaxf(nrm, 1e-30f) * 2.0f;
    const unsigned u = __float_as_uint(x);
    int si = (int)(u >> 23) - 127 + ((u & 0x7fffffu) != 0u);
    si = si < 0 ? 0 : (si > 16 ? 16 : si);
    const float c = t * __uint_as_float((unsigned)(127 - si) << 23); // t*2^-si

    const f2 cc = sp(c);
    f2 a[4][2];
    a[0][0] = r0.xy * cc;  a[0][1] = r0.zw * cc;
    a[1][0] = r1.xy * cc;  a[1][1] = r1.zw * cc;
    a[2][0] = r2.xy * cc;  a[2][1] = r2.zw * cc;
    a[3][0] = r3.xy * cc;  a[3][1] = r3.zw * cc;

    // ---- powers ----
    f2 A2[4][2], A3[4][2];
    mm4p(A2, a, a);
    mm4p(A3, A2, a);

    // ---- Paterson-Stockmeyer groups ----
    constexpr float C2 = 1.0f/2.0f,     C3 = 1.0f/6.0f;
    constexpr float C4 = 1.0f/24.0f,    C5 = 1.0f/120.0f;
    constexpr float C6 = 1.0f/720.0f,   C7 = 1.0f/5040.0f;
    constexpr float C8 = 1.0f/40320.0f, C9 = 1.0f/362880.0f;

    f2 G[4][2], HI[4][2], PI[4][2];
    #pragma unroll
    for (int i = 0; i < 4; ++i) {
        #pragma unroll
        for (int p = 0; p < 2; ++p) {
            G[i][p]  = sp(C9) * A3[i][p] + (sp(C8) * A2[i][p] + sp(C7) * a[i][p]);
            HI[i][p] = sp(C5) * A2[i][p] + sp(C4) * a[i][p];
            PI[i][p] = sp(C2) * A2[i][p] + a[i][p];
        }
    }
    G[0][0].x  += C6;   G[1][0].y  += C6;   G[2][1].x  += C6;   G[3][1].y  += C6;
    HI[0][0].x += C3;   HI[1][0].y += C3;   HI[2][1].x += C3;   HI[3][1].y += C3;
    PI[0][0].x += 1.0f; PI[1][0].y += 1.0f; PI[2][1].x += 1.0f; PI[3][1].y += 1.0f;
    // a, A2 now dead.

    // ---- H = G*A3 + HI ----
    f2 H[4][2];
    #pragma unroll
    for (int i = 0; i < 4; ++i) {
        const float g0 = G[i][0].x, g1 = G[i][0].y;
        const float g2 = G[i][1].x, g3 = G[i][1].y;
        #pragma unroll
        for (int p = 0; p < 2; ++p) {
            f2 v = HI[i][p];
            v = sp(g0) * A3[0][p] + v;
            v = sp(g1) * A3[1][p] + v;
            v = sp(g2) * A3[2][p] + v;
            v = sp(g3) * A3[3][p] + v;
            H[i][p] = v;
        }
    }

    // ---- P = H*A3 + PI ----
    f2 P[4][2];
    #pragma unroll
    for (int i = 0; i < 4; ++i) {
        const float h0 = H[i][0].x, h1 = H[i][0].y;
        const float h2 = H[i][1].x, h3 = H[i][1].y;
        #pragma unroll
        for (int p = 0; p < 2; ++p) {
            f2 v = PI[i][p];
            v = sp(h0) * A3[0][p] + v;
            v = sp(h1) * A3[1][p] + v;
            v = sp(h2) * A3[2][p] + v;
            v = sp(h3) * A3[3][p] + v;
            P[i][p] = v;
        }
    }

    // ---- undo scaling: square si times (2x ping-pong; wave pays max si) ----
    int it = si;
    while (it >= 2) {
        f2 Q[4][2];
        mm4p(Q, P, P);
        mm4p(P, Q, Q);
        it -= 2;
    }
    if (it) {
        f2 Q[4][2];
        mm4p(Q, P, P);
        #pragma unroll
        for (int i = 0; i < 4; ++i) { P[i][0] = Q[i][0]; P[i][1] = Q[i][1]; }
    }

    o0.x = P[0][0].x; o0.y = P[0][0].y; o0.z = P[0][1].x; o0.w = P[0][1].y;
    o1.x = P[1][0].x; o1.y = P[1][0].y; o1.z = P[1][1].x; o1.w = P[1][1].y;
    o2.x = P[2][0].x; o2.y = P[2][0].y; o2.z = P[2][1].x; o2.w = P[2][1].y;
    o3.x = P[3][0].x; o3.y = P[3][0].y; o3.z = P[3][1].x; o3.w = P[3][1].y;
}

__global__ void __launch_bounds__(TPB, 4) expm4_kernel(
    const float* __restrict__ A,
    const float* __restrict__ tvec,
    float* __restrict__ out,
    int M, int S, int sdivb, int tinc)
{
    const int stride = (int)gridDim.x * TPB;
    const int m0     = (int)blockIdx.x * TPB + (int)threadIdx.x;
    if (m0 >= M) return;

    const f4* __restrict__ Ap = reinterpret_cast<const f4*>(A);
    f4*       __restrict__ Op = reinterpret_cast<f4*>(out);

    // Block-uniform t-index base (SGPR arithmetic only -> s_load for t).
    const int tbase = (sdivb > 0) ? ((int)blockIdx.x / sdivb) : 0;

    f4 a0, a1, a2, a3, b0, b1, b2, b3;

    int m = m0, k = 0;
    PREF(a, Ap + (size_t)m * 4);          // prime buffer A
    int mn = m + stride;

    while (true) {
        // ---- phase A: t (uniform), prefetch->B, wait A, compute/store A ----
        {
            // t from block-uniform SGPRs only: stays a scalar load (lgkmcnt),
            // never a VMEM load whose compiler-inserted vmcnt(0) would drain
            // the asm pipeline. tinc path is exact for the bench shape.
            const float t = (tinc > 0)
                ? tvec[tbase + k * tinc]
                : (sdivb > 0)
                    ? tvec[(int)(((unsigned)blockIdx.x +
                                  (unsigned)k * gridDim.x) / (unsigned)sdivb)]
                    : tvec[m / S];
            const f4* pn = Ap + (size_t)(mn < M ? mn : m) * 4;   // clamped
            PREF(b, pn);
            WAITBUF(a);   // loads(A)+older stores done; loads(B) in flight
            f4 o0, o1, o2, o3;
            expm4_one(a0, a1, a2, a3, t, o0, o1, o2, o3);
            STORE4(Op + (size_t)m * 4, o0, o1, o2, o3);
            if (mn >= M) break;
            m = mn; ++k; mn = m + stride;
        }
        // ---- phase B: mirror ----
        {
            const float t = (tinc > 0)
                ? tvec[tbase + k * tinc]
                : (sdivb > 0)
                    ? tvec[(int)(((unsigned)blockIdx.x +
                                  (unsigned)k * gridDim.x) / (unsigned)sdivb)]
                    : tvec[m / S];
            const f4* pn = Ap + (size_t)(mn < M ? mn : m) * 4;   // clamped
            PREF(a, pn);
            WAITBUF(b);
            f4 o0, o1, o2, o3;
            expm4_one(b0, b1, b2, b3, t, o0, o1, o2, o3);
            STORE4(Op + (size_t)m * 4, o0, o1, o2, o3);
            if (mn >= M) break;
            m = mn; ++k; mn = m + stride;
        }
    }
    // drain compiler-invisible outstanding VMEM before wave exit
    asm volatile("s_waitcnt vmcnt(0)");
}

extern "C" void kernel_launch(void* const* d_in, const int* in_sizes, int n_in,
                              void* d_out, int out_size, void* d_ws, size_t ws_size,
                              hipStream_t stream) {
    const float* A    = (const float*)d_in[0];   // [B, S, 4, 4] fp32
    const float* tvec = (const float*)d_in[1];   // [B] fp32
    float* out        = (float*)d_out;           // [B, S, 4, 4] fp32

    const int B = in_sizes[1];
    const int M = in_sizes[0] / 16;              // total 4x4 matrices
    const int S = M / B;                         // matrices per batch item

    const int sdivb = (S % TPB == 0) ? (S / TPB) : 0;

    int blocks = (M + TPB * KITER - 1) / (TPB * KITER);
    if (blocks < 1) blocks = 1;

    // t-index increment per grid-stride sweep; exact when sdivb | blocks
    const int tinc = (sdivb > 0 && blocks % sdivb == 0) ? (blocks / sdivb) : 0;

    expm4_kernel<<<blocks, TPB, 0, stream>>>(A, tvec, out, M, S, sdivb, tinc);
}